// Round 7
// baseline (181.313 us; speedup 1.0000x reference)
//
#include <hip/hip_runtime.h>

#define DIM    256
#define NCODES 1024
#define BATCH  16
#define SEQ    2048
#define NROWS  (BATCH * SEQ)   // 32768
#define NTHR   256
#define NGRP   16              // 16 ng tiles of 64 codes

typedef short short8 __attribute__((ext_vector_type(8)));
typedef float f32x4 __attribute__((ext_vector_type(4)));

__device__ __forceinline__ float wave_reduce_sum(float s) {
#pragma unroll
  for (int off = 32; off > 0; off >>= 1) s += __shfl_down(s, off, 64);
  return s;
}

// round-to-nearest-even float -> bf16 (raw short)
__device__ __forceinline__ short f2bf(float f) {
  unsigned u = __builtin_bit_cast(unsigned, f);
  u = (u + 0x7fff + ((u >> 16) & 1)) >> 16;
  return (short)u;
}
__device__ __forceinline__ float bf2f(short s) {
  unsigned u = ((unsigned)(unsigned short)s) << 16;
  return __builtin_bit_cast(float, u);
}

// ---- fused prep: blocks [0,64) build bbuf+cbsq; blocks [64,80) mask/denom/init ----
// bbuf short8 index: nb16*1024 + kg*16 + m ; kg in [0,32): wh ; [32,64): wl
__global__ __launch_bounds__(NTHR) void k_prep(const float* __restrict__ cb,
                                               const float* __restrict__ mask,
                                               short8* __restrict__ bbuf,
                                               float* __restrict__ cbsq,
                                               float* __restrict__ denom,
                                               float* __restrict__ lsum,
                                               int* __restrict__ cnt) {
  const int t = threadIdx.x;
  if (blockIdx.x < 64) {
    const int nb = blockIdx.x;   // 16 codes per block
    __shared__ float tile[16 * 257];
    const float* src = cb + (size_t)nb * 16 * DIM;
#pragma unroll
    for (int i = 0; i < 16; ++i) tile[i * 257 + t] = src[i * DIM + t];
    __syncthreads();
#pragma unroll
    for (int it = 0; it < 4; ++it) {
      const int idx = it * NTHR + t;
      const int kg = idx >> 4;
      const int m = idx & 15;
      const int region = kg >> 5;
      const int k0 = (kg & 31) * 8;
      short8 v;
#pragma unroll
      for (int j = 0; j < 8; ++j) {
        const float w = tile[m * 257 + k0 + j];
        const short h = f2bf(w);
        v[j] = region ? f2bf(w - bf2f(h)) : h;
      }
      bbuf[(size_t)nb * 1024 + idx] = v;
    }
    if (t < 16) {
      float s = 0.f;
      for (int c = 0; c < DIM; ++c) { const float w = tile[t * 257 + c]; s = fmaf(w, w, s); }
      cbsq[nb * 16 + t] = s;
    }
  } else {
    const int b = blockIdx.x - 64;
    float s = 0.f;
    for (int i = t; i < SEQ; i += NTHR) s += mask[b * SEQ + i];
    s = wave_reduce_sum(s);
    __shared__ float red[NTHR / 64];
    if ((t & 63) == 0) red[t >> 6] = s;
    __syncthreads();
    if (t == 0) {
      denom[b] = red[0] + red[1] + red[2] + red[3];
      lsum[b] = 0.f;
      cnt[b] = 0;
    }
  }
}

// ---- fused convert + LDS-staged MFMA score + partial argmin, reg-prefetch pipeline ----
// Block tile: 128 rows x 128 codes. R = blockIdx&255 (so the 8 blocks sharing a feat
// row-tile share one XCD -> feat slice ~4 MB fits that XCD's L2). Ncd = blockIdx>>8.
// Per chunk: prefetch s+1 (global->VGPR), convert s (VALU), barrier, ds_write, barrier,
// ds_read + 48 MFMA. Load latency hidden behind a full compute phase.
__global__ __launch_bounds__(NTHR, 3) void k_score(const float* __restrict__ feat,
                                                   const short8* __restrict__ bbuf,
                                                   const float* __restrict__ cbsq,
                                                   float* __restrict__ pdist,
                                                   int* __restrict__ pidx) {
  __shared__ short8 sA[1024];  // 16 KB
  __shared__ short8 sB[1024];  // 16 KB
  const int t = threadIdx.x;
  const int w = t >> 6;
  const int lane = t & 63;
  const int l15 = lane & 15;
  const int quad = lane >> 4;
  const int R = blockIdx.x & 255;   // rowTile: rows R*128..
  const int Ncd = blockIdx.x >> 8;  // codeTile: codes Ncd*128..
  const int h = w >> 1;             // row half
  const int c = w & 1;              // code half

  f32x4 C[4][4];
#pragma unroll
  for (int mi = 0; mi < 4; ++mi)
#pragma unroll
    for (int ni = 0; ni < 4; ++ni) C[mi][ni] = (f32x4)0.f;

  const float4* __restrict__ fsrc = (const float4*)feat;
  const int nb0 = Ncd * 8;

  // prefetch chunk 0
  float4 pa[4];
  short8 pb[4];
#pragma unroll
  for (int i = 0; i < 2; ++i) {
    const int a = i * NTHR + t;
    const int rl = a >> 2, kgl = a & 3;
    const size_t f4 = ((size_t)R * 128 + rl) * 64 + kgl * 2;
    pa[i * 2] = fsrc[f4];
    pa[i * 2 + 1] = fsrc[f4 + 1];
  }
#pragma unroll
  for (int i = 0; i < 4; ++i) {
    const int id = i * NTHR + t;
    pb[i] = bbuf[(size_t)(nb0 + (id >> 7)) * 1024 +
                 ((((id >> 6) & 1) * 32) + ((id >> 4) & 3)) * 16 + (id & 15)];
  }

  for (int s = 0; s < 8; ++s) {
    // ---- prefetch chunk s+1 into registers (no wait until next iteration) ----
    float4 na[4];
    short8 nbv[4];
    if (s < 7) {
#pragma unroll
      for (int i = 0; i < 2; ++i) {
        const int a = i * NTHR + t;
        const int rl = a >> 2, kgl = a & 3;
        const size_t f4 = ((size_t)R * 128 + rl) * 64 + (s + 1) * 8 + kgl * 2;
        na[i * 2] = fsrc[f4];
        na[i * 2 + 1] = fsrc[f4 + 1];
      }
#pragma unroll
      for (int i = 0; i < 4; ++i) {
        const int id = i * NTHR + t;
        nbv[i] = bbuf[(size_t)(nb0 + (id >> 7)) * 1024 +
                      ((((id >> 6) & 1) * 32) + ((s + 1) * 4) + ((id >> 4) & 3)) * 16 + (id & 15)];
      }
    }
    // ---- convert current A chunk (registers only) ----
    short8 hi0[2], lo0[2];
#pragma unroll
    for (int i = 0; i < 2; ++i) {
      const float4 x0 = pa[i * 2], x1 = pa[i * 2 + 1];
      const float xs[8] = {x0.x, x0.y, x0.z, x0.w, x1.x, x1.y, x1.z, x1.w};
#pragma unroll
      for (int j = 0; j < 8; ++j) {
        const short hh = f2bf(xs[j]);
        hi0[i][j] = hh;
        lo0[i][j] = f2bf(xs[j] - bf2f(hh));
      }
    }
    __syncthreads();  // previous chunk's readers done
    // ---- LDS writes ----
#pragma unroll
    for (int i = 0; i < 2; ++i) {
      const int a = i * NTHR + t;
      const int rl = a >> 2, kgl = a & 3;
      const int rb16l = rl >> 4, m = rl & 15;
      sA[((rb16l * 2 + 0) * 4 + kgl) * 16 + m] = hi0[i];
      sA[((rb16l * 2 + 1) * 4 + kgl) * 16 + m] = lo0[i];
    }
#pragma unroll
    for (int i = 0; i < 4; ++i) sB[i * NTHR + t] = pb[i];
    __syncthreads();
    // ---- compute: frags from LDS, 48 MFMAs (hh, lh, hl) ----
    short8 ah[4], al[4], bh[4], bl[4];
#pragma unroll
    for (int mi = 0; mi < 4; ++mi) {
      ah[mi] = sA[((h * 4 + mi) * 2 + 0) * 64 + quad * 16 + l15];
      al[mi] = sA[((h * 4 + mi) * 2 + 1) * 64 + quad * 16 + l15];
    }
#pragma unroll
    for (int ni = 0; ni < 4; ++ni) {
      bh[ni] = sB[((c * 4 + ni) * 2 + 0) * 64 + quad * 16 + l15];
      bl[ni] = sB[((c * 4 + ni) * 2 + 1) * 64 + quad * 16 + l15];
    }
#pragma unroll
    for (int mi = 0; mi < 4; ++mi)
#pragma unroll
      for (int ni = 0; ni < 4; ++ni)
        C[mi][ni] = __builtin_amdgcn_mfma_f32_16x16x32_bf16(ah[mi], bh[ni], C[mi][ni], 0, 0, 0);
#pragma unroll
    for (int mi = 0; mi < 4; ++mi)
#pragma unroll
      for (int ni = 0; ni < 4; ++ni)
        C[mi][ni] = __builtin_amdgcn_mfma_f32_16x16x32_bf16(al[mi], bh[ni], C[mi][ni], 0, 0, 0);
#pragma unroll
    for (int mi = 0; mi < 4; ++mi)
#pragma unroll
      for (int ni = 0; ni < 4; ++ni)
        C[mi][ni] = __builtin_amdgcn_mfma_f32_16x16x32_bf16(ah[mi], bl[ni], C[mi][ni], 0, 0, 0);
    // ---- rotate prefetch ----
#pragma unroll
    for (int i = 0; i < 4; ++i) pa[i] = na[i];
#pragma unroll
    for (int i = 0; i < 4; ++i) pb[i] = nbv[i];
  }

  // ---- epilogue: dist = cbsq - 2*dot, per-lane then cross-lane argmin ----
  float cs[4];
#pragma unroll
  for (int ni = 0; ni < 4; ++ni) cs[ni] = cbsq[Ncd * 128 + c * 64 + ni * 16 + l15];

  float best[16];
  int bidx[16];
#pragma unroll
  for (int mi = 0; mi < 4; ++mi)
#pragma unroll
    for (int r = 0; r < 4; ++r) {
      float bd = 3.4e38f;
      int bi = 0;
#pragma unroll
      for (int ni = 0; ni < 4; ++ni) {
        const float d = fmaf(-2.f, C[mi][ni][r], cs[ni]);
        const int code = Ncd * 128 + c * 64 + ni * 16 + l15;
        if (d < bd) { bd = d; bi = code; }
      }
      best[mi * 4 + r] = bd;
      bidx[mi * 4 + r] = bi;
    }
#pragma unroll
  for (int m = 1; m <= 8; m <<= 1) {
#pragma unroll
    for (int j = 0; j < 16; ++j) {
      const float od = __shfl_xor(best[j], m, 64);
      const int oi = __shfl_xor(bidx[j], m, 64);
      if (od < best[j] || (od == best[j] && oi < bidx[j])) { best[j] = od; bidx[j] = oi; }
    }
  }
  if (l15 == 0) {
    const int ng = Ncd * 2 + c;
#pragma unroll
    for (int mi = 0; mi < 4; ++mi)
#pragma unroll
      for (int r = 0; r < 4; ++r) {
        const int row = R * 128 + h * 64 + mi * 16 + quad * 4 + r;
        pdist[row * NGRP + ng] = best[mi * 4 + r];
        pidx[row * NGRP + ng] = bidx[mi * 4 + r];
      }
  }
}

// ---- fused merge + gather + ST out + masked MSE + (last block) finalize ----
__global__ __launch_bounds__(NTHR) void k_gather(const float* __restrict__ feat,
                                                 const float* __restrict__ cb,
                                                 const float* __restrict__ mask,
                                                 const float* __restrict__ pdist,
                                                 const int* __restrict__ pidx,
                                                 const float* __restrict__ denom,
                                                 float* __restrict__ outq,
                                                 float* __restrict__ outl,
                                                 float* __restrict__ lsum,
                                                 int* __restrict__ cnt) {
  const int t = threadIdx.x;
  const int row0 = blockIdx.x * 64;
  __shared__ float sd[NTHR];
  __shared__ int si[NTHR];
  __shared__ int skid[64];
  {
    const float4 pd = ((const float4*)pdist)[row0 * 4 + t];
    const int4 pi = ((const int4*)pidx)[row0 * 4 + t];
    float bd = pd.x; int bi = pi.x;
    if (pd.y < bd || (pd.y == bd && pi.y < bi)) { bd = pd.y; bi = pi.y; }
    if (pd.z < bd || (pd.z == bd && pi.z < bi)) { bd = pd.z; bi = pi.z; }
    if (pd.w < bd || (pd.w == bd && pi.w < bi)) { bd = pd.w; bi = pi.w; }
    sd[t] = bd; si[t] = bi;
  }
  __syncthreads();
  if (t < 64) {
    float bd = sd[t * 4]; int bi = si[t * 4];
#pragma unroll
    for (int j = 1; j < 4; ++j) {
      const float od = sd[t * 4 + j]; const int oi = si[t * 4 + j];
      if (od < bd || (od == bd && oi < bi)) { bd = od; bi = oi; }
    }
    skid[t] = bi;
  }
  __syncthreads();
  const int wv = t >> 6;
  const int dg = t & 63;
  const int b = row0 >> 11;
  float acc = 0.f;
#pragma unroll
  for (int i = 0; i < 16; ++i) {
    const int r = wv * 16 + i;
    const size_t row = row0 + r;
    const int k = skid[r];
    const float4 q = ((const float4*)cb)[k * (DIM / 4) + dg];
    const float4 x = ((const float4*)feat)[row * (DIM / 4) + dg];
    float4 o;
    o.x = x.x + (q.x - x.x);
    o.y = x.y + (q.y - x.y);
    o.z = x.z + (q.z - x.z);
    o.w = x.w + (q.w - x.w);
    ((float4*)outq)[row * (DIM / 4) + dg] = o;
    const float m = mask[row];
    const float dx = x.x - q.x, dy = x.y - q.y, dz = x.z - q.z, dw = x.w - q.w;
    acc = fmaf(m, dx * dx + dy * dy + dz * dz + dw * dw, acc);
  }
  acc = wave_reduce_sum(acc);
  __shared__ float red[4];
  if ((t & 63) == 0) red[wv] = acc;
  __syncthreads();
  if (t == 0) {
    atomicAdd(&lsum[b], red[0] + red[1] + red[2] + red[3]);
    __threadfence();
    const int old = atomicAdd(&cnt[b], 1);
    if (old == (SEQ / 64) - 1) {  // last of the 32 blocks for this batch
      __threadfence();
      const float tot = atomicAdd(&lsum[b], 0.f);  // device-scope read
      const float v = tot / denom[b];
      outl[b] = v;          // quant_loss
      outl[BATCH + b] = v;  // commit_loss (identical in forward)
    }
  }
}

extern "C" void kernel_launch(void* const* d_in, const int* in_sizes, int n_in,
                              void* d_out, int out_size, void* d_ws, size_t ws_size,
                              hipStream_t stream) {
  const float* feat = (const float*)d_in[0];  // [16,2048,256]
  const float* mask = (const float*)d_in[1];  // [16,2048]
  const float* cb   = (const float*)d_in[2];  // [1024,256]
  float* out = (float*)d_out;

  char* p = (char*)d_ws;
  short8* bbuf = (short8*)p;                 p += (size_t)NCODES * 512 * 2;  // 1.05 MB
  float* cbsq  = (float*)p;                  p += NCODES * 4;
  float* pdist = (float*)p;                  p += (size_t)NROWS * NGRP * 4;  // 2 MB
  int*   pidx  = (int*)p;                    p += (size_t)NROWS * NGRP * 4;  // 2 MB
  float* denom = (float*)p;                  p += BATCH * 4;
  float* lsum  = (float*)p;                  p += BATCH * 4;
  int*   cnt   = (int*)p;

  k_prep<<<80, NTHR, 0, stream>>>(cb, mask, bbuf, cbsq, denom, lsum, cnt);
  k_score<<<2048, NTHR, 0, stream>>>(feat, bbuf, cbsq, pdist, pidx);
  k_gather<<<NROWS / 64, NTHR, 0, stream>>>(feat, cb, mask, pdist, pidx, denom,
                                            out, out + (size_t)NROWS * DIM, lsum, cnt);
}

// Round 8
// 181.172 us; speedup vs baseline: 1.0008x; 1.0008x over previous
//
#include <hip/hip_runtime.h>

#define DIM    256
#define NCODES 1024
#define BATCH  16
#define SEQ    2048
#define NROWS  (BATCH * SEQ)   // 32768
#define NTHR   256
#define NGRP   16              // 16 ng tiles of 64 codes
#define APAD   18              // kgl-run stride in short8 (16 data + 2 pad): 288 B = 8 banks mod 32

typedef short short8 __attribute__((ext_vector_type(8)));
typedef float f32x4 __attribute__((ext_vector_type(4)));

__device__ __forceinline__ float wave_reduce_sum(float s) {
#pragma unroll
  for (int off = 32; off > 0; off >>= 1) s += __shfl_down(s, off, 64);
  return s;
}

// round-to-nearest-even float -> bf16 (raw short)
__device__ __forceinline__ short f2bf(float f) {
  unsigned u = __builtin_bit_cast(unsigned, f);
  u = (u + 0x7fff + ((u >> 16) & 1)) >> 16;
  return (short)u;
}
__device__ __forceinline__ float bf2f(short s) {
  unsigned u = ((unsigned)(unsigned short)s) << 16;
  return __builtin_bit_cast(float, u);
}

// ---- fused prep: blocks [0,64) build bbuf+cbsq; blocks [64,80) mask/denom/init ----
// bbuf short8 index: nb16*1024 + kg*16 + m ; kg in [0,32): wh ; [32,64): wl
__global__ __launch_bounds__(NTHR) void k_prep(const float* __restrict__ cb,
                                               const float* __restrict__ mask,
                                               short8* __restrict__ bbuf,
                                               float* __restrict__ cbsq,
                                               float* __restrict__ denom,
                                               float* __restrict__ lsum,
                                               int* __restrict__ cnt) {
  const int t = threadIdx.x;
  if (blockIdx.x < 64) {
    const int nb = blockIdx.x;   // 16 codes per block
    __shared__ float tile[16 * 257];
    const float* src = cb + (size_t)nb * 16 * DIM;
#pragma unroll
    for (int i = 0; i < 16; ++i) tile[i * 257 + t] = src[i * DIM + t];
    __syncthreads();
#pragma unroll
    for (int it = 0; it < 4; ++it) {
      const int idx = it * NTHR + t;
      const int kg = idx >> 4;
      const int m = idx & 15;
      const int region = kg >> 5;
      const int k0 = (kg & 31) * 8;
      short8 v;
#pragma unroll
      for (int j = 0; j < 8; ++j) {
        const float w = tile[m * 257 + k0 + j];
        const short h = f2bf(w);
        v[j] = region ? f2bf(w - bf2f(h)) : h;
      }
      bbuf[(size_t)nb * 1024 + idx] = v;
    }
    if (t < 16) {
      float s = 0.f;
      for (int c = 0; c < DIM; ++c) { const float w = tile[t * 257 + c]; s = fmaf(w, w, s); }
      cbsq[nb * 16 + t] = s;
    }
  } else {
    const int b = blockIdx.x - 64;
    float s = 0.f;
    for (int i = t; i < SEQ; i += NTHR) s += mask[b * SEQ + i];
    s = wave_reduce_sum(s);
    __shared__ float red[NTHR / 64];
    if ((t & 63) == 0) red[t >> 6] = s;
    __syncthreads();
    if (t == 0) {
      denom[b] = red[0] + red[1] + red[2] + red[3];
      lsum[b] = 0.f;
      cnt[b] = 0;
    }
  }
}

// ---- fused convert + A-only LDS + direct-global-B MFMA score + partial argmin ----
// Block 128 rows x 128 codes; R = blockIdx&255 (8 code-tiles of one row-tile share an
// XCD: feat slice 4 MB -> L2-resident re-reads), Ncd = blockIdx>>8.
// Per chunk (k=32): load A f32 (coalesced) -> convert hi/lo -> barrier -> ds_write
// (conflict-free via APAD) -> barrier -> issue 8 coalesced B loads (L2-hot bbuf) ->
// 8 ds_read_b128 A frags -> 48 MFMAs (hh, lh, hl).
__global__ __launch_bounds__(NTHR, 3) void k_score(const float* __restrict__ feat,
                                                   const short8* __restrict__ bbuf,
                                                   const float* __restrict__ cbsq,
                                                   float* __restrict__ pdist,
                                                   int* __restrict__ pidx) {
  __shared__ short8 sA[64 * APAD];  // 18 KB: runs [rb16l(8)][reg(2)][kgl(4)] x APAD
  const int t = threadIdx.x;
  const int w = t >> 6;
  const int lane = t & 63;
  const int l15 = lane & 15;
  const int quad = lane >> 4;
  const int R = blockIdx.x & 255;
  const int Ncd = blockIdx.x >> 8;
  const int h = w >> 1;             // row half
  const int c = w & 1;              // code half

  f32x4 C[4][4];
#pragma unroll
  for (int mi = 0; mi < 4; ++mi)
#pragma unroll
    for (int ni = 0; ni < 4; ++ni) C[mi][ni] = (f32x4)0.f;

  const float4* __restrict__ fsrc = (const float4*)feat;
  const int nb0 = Ncd * 8;

  for (int s = 0; s < 8; ++s) {
    // ---- load + convert A chunk (no LDS deps) ----
    short8 hi0[2], lo0[2];
#pragma unroll
    for (int i = 0; i < 2; ++i) {
      const int a = i * NTHR + t;
      const int rl = a >> 2, kgl = a & 3;
      const size_t f4 = ((size_t)R * 128 + rl) * 64 + s * 8 + kgl * 2;
      const float4 x0 = fsrc[f4];
      const float4 x1 = fsrc[f4 + 1];
      const float xs[8] = {x0.x, x0.y, x0.z, x0.w, x1.x, x1.y, x1.z, x1.w};
#pragma unroll
      for (int j = 0; j < 8; ++j) {
        const short hh = f2bf(xs[j]);
        hi0[i][j] = hh;
        lo0[i][j] = f2bf(xs[j] - bf2f(hh));
      }
    }
    __syncthreads();  // previous chunk's readers done
#pragma unroll
    for (int i = 0; i < 2; ++i) {
      const int a = i * NTHR + t;
      const int rl = a >> 2, kgl = a & 3;
      const int rb16l = rl >> 4, m = rl & 15;
      sA[(((rb16l * 2 + 0) * 4) + kgl) * APAD + m] = hi0[i];
      sA[(((rb16l * 2 + 1) * 4) + kgl) * APAD + m] = lo0[i];
    }
    __syncthreads();
    // ---- B fragments direct from global (coalesced 1 KB/wave, L2-hot) ----
    short8 bh[4], bl[4];
#pragma unroll
    for (int ni = 0; ni < 4; ++ni) {
      const size_t base = (size_t)(nb0 + c * 4 + ni) * 1024 + (s * 4 + quad) * 16 + l15;
      bh[ni] = bbuf[base];         // reg=0: wh
      bl[ni] = bbuf[base + 512];   // reg=1: wl (offset 32*16)
    }
    // ---- A fragments from LDS ----
    short8 ah[4], al[4];
#pragma unroll
    for (int mi = 0; mi < 4; ++mi) {
      ah[mi] = sA[((((h * 4 + mi) * 2 + 0) * 4) + quad) * APAD + l15];
      al[mi] = sA[((((h * 4 + mi) * 2 + 1) * 4) + quad) * APAD + l15];
    }
    // ---- 48 MFMAs: hh, lh, hl (same FP order as previous rounds) ----
#pragma unroll
    for (int mi = 0; mi < 4; ++mi)
#pragma unroll
      for (int ni = 0; ni < 4; ++ni)
        C[mi][ni] = __builtin_amdgcn_mfma_f32_16x16x32_bf16(ah[mi], bh[ni], C[mi][ni], 0, 0, 0);
#pragma unroll
    for (int mi = 0; mi < 4; ++mi)
#pragma unroll
      for (int ni = 0; ni < 4; ++ni)
        C[mi][ni] = __builtin_amdgcn_mfma_f32_16x16x32_bf16(al[mi], bh[ni], C[mi][ni], 0, 0, 0);
#pragma unroll
    for (int mi = 0; mi < 4; ++mi)
#pragma unroll
      for (int ni = 0; ni < 4; ++ni)
        C[mi][ni] = __builtin_amdgcn_mfma_f32_16x16x32_bf16(ah[mi], bl[ni], C[mi][ni], 0, 0, 0);
  }

  // ---- epilogue: dist = cbsq - 2*dot, per-lane then cross-lane argmin ----
  float cs[4];
#pragma unroll
  for (int ni = 0; ni < 4; ++ni) cs[ni] = cbsq[Ncd * 128 + c * 64 + ni * 16 + l15];

  float best[16];
  int bidx[16];
#pragma unroll
  for (int mi = 0; mi < 4; ++mi)
#pragma unroll
    for (int r = 0; r < 4; ++r) {
      float bd = 3.4e38f;
      int bi = 0;
#pragma unroll
      for (int ni = 0; ni < 4; ++ni) {
        const float d = fmaf(-2.f, C[mi][ni][r], cs[ni]);
        const int code = Ncd * 128 + c * 64 + ni * 16 + l15;
        if (d < bd) { bd = d; bi = code; }
      }
      best[mi * 4 + r] = bd;
      bidx[mi * 4 + r] = bi;
    }
#pragma unroll
  for (int m = 1; m <= 8; m <<= 1) {
#pragma unroll
    for (int j = 0; j < 16; ++j) {
      const float od = __shfl_xor(best[j], m, 64);
      const int oi = __shfl_xor(bidx[j], m, 64);
      if (od < best[j] || (od == best[j] && oi < bidx[j])) { best[j] = od; bidx[j] = oi; }
    }
  }
  if (l15 == 0) {
    const int ng = Ncd * 2 + c;
#pragma unroll
    for (int mi = 0; mi < 4; ++mi)
#pragma unroll
      for (int r = 0; r < 4; ++r) {
        const int row = R * 128 + h * 64 + mi * 16 + quad * 4 + r;
        pdist[row * NGRP + ng] = best[mi * 4 + r];
        pidx[row * NGRP + ng] = bidx[mi * 4 + r];
      }
  }
}

// ---- fused merge + gather + ST out + masked MSE + (last block per batch) finalize ----
__global__ __launch_bounds__(NTHR) void k_gather(const float* __restrict__ feat,
                                                 const float* __restrict__ cb,
                                                 const float* __restrict__ mask,
                                                 const float* __restrict__ pdist,
                                                 const int* __restrict__ pidx,
                                                 const float* __restrict__ denom,
                                                 float* __restrict__ outq,
                                                 float* __restrict__ outl,
                                                 float* __restrict__ lsum,
                                                 int* __restrict__ cnt) {
  const int t = threadIdx.x;
  const int row0 = blockIdx.x * 64;
  __shared__ float sd[NTHR];
  __shared__ int si[NTHR];
  __shared__ int skid[64];
  {
    const float4 pd = ((const float4*)pdist)[row0 * 4 + t];
    const int4 pi = ((const int4*)pidx)[row0 * 4 + t];
    float bd = pd.x; int bi = pi.x;
    if (pd.y < bd || (pd.y == bd && pi.y < bi)) { bd = pd.y; bi = pi.y; }
    if (pd.z < bd || (pd.z == bd && pi.z < bi)) { bd = pd.z; bi = pi.z; }
    if (pd.w < bd || (pd.w == bd && pi.w < bi)) { bd = pd.w; bi = pi.w; }
    sd[t] = bd; si[t] = bi;
  }
  __syncthreads();
  if (t < 64) {
    float bd = sd[t * 4]; int bi = si[t * 4];
#pragma unroll
    for (int j = 1; j < 4; ++j) {
      const float od = sd[t * 4 + j]; const int oi = si[t * 4 + j];
      if (od < bd || (od == bd && oi < bi)) { bd = od; bi = oi; }
    }
    skid[t] = bi;
  }
  __syncthreads();
  const int wv = t >> 6;
  const int dg = t & 63;
  const int b = row0 >> 11;
  float acc = 0.f;
#pragma unroll
  for (int i = 0; i < 16; ++i) {
    const int r = wv * 16 + i;
    const size_t row = row0 + r;
    const int k = skid[r];
    const float4 q = ((const float4*)cb)[k * (DIM / 4) + dg];
    const float4 x = ((const float4*)feat)[row * (DIM / 4) + dg];
    float4 o;
    o.x = x.x + (q.x - x.x);
    o.y = x.y + (q.y - x.y);
    o.z = x.z + (q.z - x.z);
    o.w = x.w + (q.w - x.w);
    ((float4*)outq)[row * (DIM / 4) + dg] = o;
    const float m = mask[row];
    const float dx = x.x - q.x, dy = x.y - q.y, dz = x.z - q.z, dw = x.w - q.w;
    acc = fmaf(m, dx * dx + dy * dy + dz * dz + dw * dw, acc);
  }
  acc = wave_reduce_sum(acc);
  __shared__ float red[4];
  if ((t & 63) == 0) red[wv] = acc;
  __syncthreads();
  if (t == 0) {
    atomicAdd(&lsum[b], red[0] + red[1] + red[2] + red[3]);
    __threadfence();
    const int old = atomicAdd(&cnt[b], 1);
    if (old == (SEQ / 64) - 1) {
      __threadfence();
      const float tot = atomicAdd(&lsum[b], 0.f);  // device-scope read of final sum
      const float v = tot / denom[b];
      outl[b] = v;          // quant_loss
      outl[BATCH + b] = v;  // commit_loss (identical in forward)
    }
  }
}

extern "C" void kernel_launch(void* const* d_in, const int* in_sizes, int n_in,
                              void* d_out, int out_size, void* d_ws, size_t ws_size,
                              hipStream_t stream) {
  const float* feat = (const float*)d_in[0];  // [16,2048,256]
  const float* mask = (const float*)d_in[1];  // [16,2048]
  const float* cb   = (const float*)d_in[2];  // [1024,256]
  float* out = (float*)d_out;

  char* p = (char*)d_ws;
  short8* bbuf = (short8*)p;                 p += (size_t)NCODES * 512 * 2;  // 1.05 MB
  float* cbsq  = (float*)p;                  p += NCODES * 4;
  float* pdist = (float*)p;                  p += (size_t)NROWS * NGRP * 4;  // 2 MB
  int*   pidx  = (int*)p;                    p += (size_t)NROWS * NGRP * 4;  // 2 MB
  float* denom = (float*)p;                  p += BATCH * 4;
  float* lsum  = (float*)p;                  p += BATCH * 4;
  int*   cnt   = (int*)p;

  k_prep<<<80, NTHR, 0, stream>>>(cb, mask, bbuf, cbsq, denom, lsum, cnt);
  k_score<<<2048, NTHR, 0, stream>>>(feat, bbuf, cbsq, pdist, pidx);
  k_gather<<<NROWS / 64, NTHR, 0, stream>>>(feat, cb, mask, pdist, pidx, denom,
                                            out, out + (size_t)NROWS * DIM, lsum, cnt);
}